// Round 2
// 115.745 us; speedup vs baseline: 1.2144x; 1.2144x over previous
//
#include <hip/hip_runtime.h>
#include <stdint.h>

#define B 4
#define T 256
#define V 1024
#define S 64
#define DIM 1024
#define CV 256

typedef __attribute__((ext_vector_type(8))) short bf16x8;
typedef __attribute__((ext_vector_type(4))) short s16x4;
typedef __attribute__((ext_vector_type(4))) float f32x4;

// ---- workspace layout (4-byte word offsets; bf16 arrays counted in words) ----
// No zero-init required anywhere: every cell is unconditionally written each
// launch before it is read (harness poisons ws with 0xAA).
enum : int {
    WKT_O   = 0,                  // [262144 w] WkT bf16 [DIM][DIM] (d-major)
    WVT_O   = WKT_O + 262144,     // [262144 w] WvT bf16 [DIM][DIM]
    WUB_O   = WVT_O + 262144,     // [131072 w] Wu bf16 [CV][DIM]
    WKPB_O  = WUB_O + 131072,     // [131072 w] Wkp bf16 [CV][DIM]   (B^T for z)
    WVPT_O  = WKPB_O + 131072,    // [131072 w] WvpT bf16 [DIM][CV]  (B^T for out)
    XB_O    = WVPT_O + 131072,    // [262144 w] x bf16 [B*T][DIM]
    ZB_O    = XB_O + 262144,      // [131072 w] Z bf16 [B*T][CV]
    VB_O    = ZB_O + 131072,      // [524288 w] vision bf16 [B][V][CV]
    WB_O    = VB_O + 524288,      // [131072 w] W bf16 [B*T][CV]
    RS_O    = WB_O + 131072,      // [B*T] f32 row sums
    PIDX_O  = RS_O + B*T,         // [B*T*S] int selected v
    BK_O    = PIDX_O + B*T*S,     // [DIM] f32 bu@Wk  (written by g_prep blk 512)
    BV_O    = BK_O + DIM,         // [DIM] f32 bu@Wv  (written by g_prep blk 513)
    BP_O    = BV_O + DIM,         // [2][16][1024] f32 bias partials (stage1)
    WS_TOTAL= BP_O + 2*16*1024
};

__device__ __forceinline__ short f2bf(float f) {
    union { float f; unsigned u; } x; x.f = f;
    unsigned r = (x.u + 0x7FFF + ((x.u >> 16) & 1)) >> 16;
    return (short)r;
}
__device__ __forceinline__ float bf2f(short s) {
    union { unsigned u; float f; } x;
    x.u = ((unsigned)(unsigned short)s) << 16;
    return x.f;
}
__device__ __forceinline__ s16x4 cvt4(float4 f) {
    s16x4 o;
    o.x = f2bf(f.x); o.y = f2bf(f.y); o.z = f2bf(f.z); o.w = f2bf(f.w);
    return o;
}

// ================= stage 1: all input conversion + mask compaction =============
// blocks [0,1024)    : vision f32 -> bf16
// blocks [1024,1280) : Wu f32 -> bf16
// blocks [1280,2304) : x f32 -> bf16
// blocks [2304,2816) : Wk/Wv transpose-convert -> bf16 [d][e] + bias partials
// blocks [2816,2880) : mask compaction (self-detecting encoding)
__global__ void stage1(const float* __restrict__ vision, const float* __restrict__ Wu,
                       const float* __restrict__ x, const float* __restrict__ Wk,
                       const float* __restrict__ Wv, const float* __restrict__ bu,
                       const void* __restrict__ maskp,
                       float* __restrict__ ws, int* __restrict__ wsi) {
    __shared__ short tlds[64 * 65];
    __shared__ float tred[4 * 64];
    __shared__ int mc_cnt[16][17];
    __shared__ int sa_flag, sb_flag;
    int blk = blockIdx.x;
    int tid = threadIdx.x;

    if (blk < 2304) {  // ---- straight f32 -> bf16 converts ----
        const float* src; short* dst; int idx;
        if (blk < 1024)      { src = vision; dst = (short*)(ws + VB_O);  idx = blk; }
        else if (blk < 1280) { src = Wu;     dst = (short*)(ws + WUB_O); idx = blk - 1024; }
        else                 { src = x;      dst = (short*)(ws + XB_O);  idx = blk - 1280; }
        int i = (idx * 256 + tid);
        ((s16x4*)dst)[i] = cvt4(((const float4*)src)[i]);
        return;
    }
    if (blk < 2816) {  // ---- transpose-convert Wk/Wv + bias partials (no atomics) ----
        int tile = blk - 2304;
        int which = tile >> 8, t2 = tile & 255;
        int e0 = (t2 >> 4) * 64, d0 = (t2 & 15) * 64;
        const float* src = which ? Wv : Wk;
        short* dst = (short*)(ws + (which ? WVT_O : WKT_O));
        int j = tid & 63, i0 = tid >> 6;
        float pb = 0.f;
#pragma unroll
        for (int p = 0; p < 16; p++) {
            int i = p * 4 + i0;
            float v = src[(size_t)(e0 + i) * DIM + d0 + j];
            tlds[j * 65 + i] = f2bf(v);
            pb += bu[e0 + i] * v;
        }
        tred[i0 * 64 + j] = pb;
        __syncthreads();
#pragma unroll
        for (int p = 0; p < 16; p++) {
            int dd = p * 4 + i0;
            dst[(size_t)(d0 + dd) * DIM + e0 + j] = tlds[dd * 65 + j];
        }
        if (i0 == 0) {
            float s = tred[j] + tred[64 + j] + tred[128 + j] + tred[192 + j];
            ws[BP_O + (which * 16 + (e0 >> 6)) * 1024 + d0 + j] = s;
        }
        return;
    }
    // ---- mask compaction with block-local encoding detection ----
    {
        int a = 0, bfl = 0;
        const uchar4* m4 = (const uchar4*)maskp;
#pragma unroll
        for (int jj = 0; jj < 4; jj++) {
            uchar4 u = m4[tid * 4 + jj];
            if (u.y | u.z | u.w) a = 1;
            if (u.x == 0x3f || u.y == 0x3f || u.z == 0x3f || u.w == 0x3f) bfl = 1;
        }
        if (tid == 0) { sa_flag = 0; sb_flag = 0; }
        __syncthreads();
        if (a) sa_flag = 1;
        if (bfl) sb_flag = 1;
        __syncthreads();
    }
    bool byteMode = sa_flag && !sb_flag;
    int mb = blk - 2816;
    int b = mb >> 4, tg = mb & 15;
    int tl = tid & 15, c = tid >> 4;
    int t = tg * 16 + tl;
    int v0 = c * 64;
    unsigned long long bits = 0ull;
    if (byteMode) {
        const uint8_t* m = (const uint8_t*)maskp + (size_t)(b * V + v0) * T + t;
#pragma unroll 8
        for (int j = 0; j < 64; j++)
            if (m[(size_t)j * T] != 0) bits |= 1ull << j;
    } else {
        const int* m = (const int*)maskp + (size_t)(b * V + v0) * T + t;
#pragma unroll 8
        for (int j = 0; j < 64; j++)
            if (m[(size_t)j * T] != 0) bits |= 1ull << j;
    }
    mc_cnt[tl][c] = __popcll(bits);
    __syncthreads();
    int off = 0, total = 0;
#pragma unroll
    for (int cc = 0; cc < 16; cc++) {
        int cn = mc_cnt[tl][cc];
        if (cc < c) off += cn;
        total += cn;
    }
    int base = PIDX_O + (b * T + t) * S;
    while (bits) {
        int j = __ffsll(bits) - 1;
        bits &= bits - 1;
        if (off < S) wsi[base + off] = v0 + j;
        off++;
    }
    if (c == 15)
        for (int j = (total < S ? total : S); j < S; j++) wsi[base + j] = 0;
}

// ---- per-wave 32x32 MFMA tile: A[m][k] row-major, Bt[n][k] row-major ----
template<int K, int LDA, int LDB>
__device__ __forceinline__ void wave_mma(const short* __restrict__ A0,
                                         const short* __restrict__ B0,
                                         f32x4 acc[2][2]) {
    int lane = threadIdx.x & 63;
    int rw = lane & 15, q = lane >> 4;
    const short* ap0 = A0 + rw * LDA + q * 8;
    const short* ap1 = ap0 + 16 * LDA;
    const short* bp0 = B0 + rw * LDB + q * 8;
    const short* bp1 = bp0 + 16 * LDB;
#pragma unroll 4
    for (int kc = 0; kc < K; kc += 32) {
        bf16x8 a0 = *(const bf16x8*)(ap0 + kc);
        bf16x8 a1 = *(const bf16x8*)(ap1 + kc);
        bf16x8 b0 = *(const bf16x8*)(bp0 + kc);
        bf16x8 b1 = *(const bf16x8*)(bp1 + kc);
        acc[0][0] = __builtin_amdgcn_mfma_f32_16x16x32_bf16(a0, b0, acc[0][0], 0, 0, 0);
        acc[0][1] = __builtin_amdgcn_mfma_f32_16x16x32_bf16(a0, b1, acc[0][1], 0, 0, 0);
        acc[1][0] = __builtin_amdgcn_mfma_f32_16x16x32_bf16(a1, b0, acc[1][0], 0, 0, 0);
        acc[1][1] = __builtin_amdgcn_mfma_f32_16x16x32_bf16(a1, b1, acc[1][1], 0, 0, 0);
    }
}

// ---- split-K reduction helper: waves 1..3 dump acc to LDS (padded to kill
// ---- bank conflicts), wave 0 accumulates. Returns true if this wave stores. --
__device__ __forceinline__ bool splitk_reduce(f32x4 acc[2][2],
                                              float (*red)[64][17],
                                              int wv, int lane) {
    if (wv > 0) {
#pragma unroll
        for (int i = 0; i < 2; i++)
#pragma unroll
            for (int j = 0; j < 2; j++)
#pragma unroll
                for (int r = 0; r < 4; r++)
                    red[wv - 1][lane][(i * 2 + j) * 4 + r] = acc[i][j][r];
    }
    __syncthreads();
    if (wv != 0) return false;
#pragma unroll
    for (int i = 0; i < 2; i++)
#pragma unroll
        for (int j = 0; j < 2; j++)
#pragma unroll
            for (int r = 0; r < 4; r++) {
                int c = (i * 2 + j) * 4 + r;
                acc[i][j][r] += red[0][lane][c] + red[1][lane][c] + red[2][lane][c];
            }
    return true;
}

// ---- g_prep: blocks 0..511: one 32x32 tile each, 4 waves split K=1024 into
// ---- 256-slices (2 blocks/CU, short per-wave chains). Blocks 512/513: bias. --
__global__ void g_prep_mfma(float* __restrict__ ws) {
    if (blockIdx.x >= 512) {
        int which = blockIdx.x - 512;
#pragma unroll
        for (int cch = 0; cch < 4; cch++) {
            int d = cch * 256 + threadIdx.x;
            float s = 0.f;
#pragma unroll
            for (int g = 0; g < 16; g++)
                s += ws[BP_O + (which * 16 + g) * 1024 + d];
            ws[(which ? BV_O : BK_O) + d] = s;
        }
        return;
    }
    __shared__ float red[3][64][17];
    int tile = blockIdx.x;                           // 512 tiles
    int which = tile >> 8, rem = tile & 255;
    int m0 = (rem >> 5) * 32, n0 = (rem & 31) * 32;  // m: cv(256), n: d(1024)
    int wv = threadIdx.x >> 6, lane = threadIdx.x & 63;
    const short* A = (const short*)(ws + WUB_O) + (size_t)m0 * DIM + wv * 256;
    const short* Bt = (const short*)(ws + (which ? WVT_O : WKT_O)) + (size_t)n0 * DIM + wv * 256;
    f32x4 acc[2][2] = {};
    wave_mma<256, DIM, DIM>(A, Bt, acc);
    if (!splitk_reduce(acc, red, wv, lane)) return;
    int col = lane & 15, q = lane >> 4;
    if (which == 0) {
        short* o = (short*)(ws + WKPB_O);
#pragma unroll
        for (int i = 0; i < 2; i++)
#pragma unroll
            for (int j = 0; j < 2; j++)
#pragma unroll
                for (int r = 0; r < 4; r++)
                    o[(size_t)(m0 + i * 16 + q * 4 + r) * DIM + n0 + j * 16 + col] =
                        f2bf(acc[i][j][r]);
    } else {
        short* o = (short*)(ws + WVPT_O);
#pragma unroll
        for (int i = 0; i < 2; i++)
#pragma unroll
            for (int j = 0; j < 2; j++) {
                s16x4 v;
                v.x = f2bf(acc[i][j][0]); v.y = f2bf(acc[i][j][1]);
                v.z = f2bf(acc[i][j][2]); v.w = f2bf(acc[i][j][3]);
                *(s16x4*)&o[(size_t)(n0 + j * 16 + col) * CV + m0 + i * 16 + q * 4] = v;
            }
    }
}

// ---- g_z: Z bf16 [bt][cv] = Xb @ Wkp^T; 256 blocks, one 32x32 tile each,
// ---- 4 waves split K=1024 (was 64 blocks / quarter-GPU). ----
__global__ void g_z_mfma(float* __restrict__ ws) {
    __shared__ float red[3][64][17];
    int w = blockIdx.x;                            // 256 tiles
    int m0 = (w >> 3) * 32, n0 = (w & 7) * 32;     // m: bt(1024), n: cv(256)
    int wv = threadIdx.x >> 6, lane = threadIdx.x & 63;
    const short* A = (const short*)(ws + XB_O) + (size_t)m0 * DIM + wv * 256;
    const short* Bt = (const short*)(ws + WKPB_O) + (size_t)n0 * DIM + wv * 256;
    f32x4 acc[2][2] = {};
    wave_mma<256, DIM, DIM>(A, Bt, acc);
    if (!splitk_reduce(acc, red, wv, lane)) return;
    int col = lane & 15, q = lane >> 4;
    short* zb = (short*)(ws + ZB_O);
#pragma unroll
    for (int i = 0; i < 2; i++)
#pragma unroll
        for (int j = 0; j < 2; j++)
#pragma unroll
            for (int r = 0; r < 4; r++)
                zb[(size_t)(m0 + i * 16 + q * 4 + r) * CV + n0 + j * 16 + col] =
                    f2bf(acc[i][j][r]);
}

// ---- g_attn: 512 blocks x 4 waves; each PAIR of waves handles one (b,t):
// ---- wave h does half of c0, half the score tiles, half the W accumulation. --
__global__ void g_attn(const float* __restrict__ x, float* __restrict__ ws,
                       int* __restrict__ wsi) {
    __shared__ int   s_idx[2][64];
    __shared__ float s_sc[2][64];
    __shared__ float s_c0[2][2];
    __shared__ float s_p[2][64];
    __shared__ float s_wa[2][64][5];   // pad 4->5: conflict-free
    int tid = threadIdx.x;
    int lane = tid & 63, wv = tid >> 6;
    int pair = wv >> 1, h = wv & 1;
    int bt = blockIdx.x * 2 + pair, b = bt >> 8;
    if (h == 0) s_idx[pair][lane] = wsi[PIDX_O + bt * S + lane];    // S == 64
    // c0 = x[bt] . bk : each wave covers half of DIM
    float c0p = 0.f;
    const float4* xr = (const float4*)(x + (size_t)bt * DIM);
    const float4* bkr = (const float4*)(ws + BK_O);
#pragma unroll
    for (int j = 0; j < 2; j++) {
        int jj = h * 2 + j;
        float4 a = xr[lane + 64 * jj], k4 = bkr[lane + 64 * jj];
        c0p += a.x * k4.x + a.y * k4.y + a.z * k4.z + a.w * k4.w;
    }
    for (int o = 32; o > 0; o >>= 1) c0p += __shfl_xor(c0p, o);
    if (lane == 0) s_c0[pair][h] = c0p;
    __syncthreads();
    // scores: wave h computes score tiles mt = 2h, 2h+1 (16 rows each)
    int rw = lane & 15, q = lane >> 4;
    const short* vb = (const short*)(ws + VB_O) + (size_t)b * V * CV;
    const short* zp = (const short*)(ws + ZB_O) + (size_t)bt * CV + q * 8;
#pragma unroll
    for (int mi = 0; mi < 2; mi++) {
        int mt = h * 2 + mi;
        const short* ap = vb + (size_t)s_idx[pair][mt * 16 + rw] * CV + q * 8;
        f32x4 a4 = {0.f, 0.f, 0.f, 0.f};
#pragma unroll
        for (int kc = 0; kc < CV; kc += 32) {
            bf16x8 av = *(const bf16x8*)(ap + kc);
            bf16x8 bv = *(const bf16x8*)(zp + kc);
            a4 = __builtin_amdgcn_mfma_f32_16x16x32_bf16(av, bv, a4, 0, 0, 0);
        }
        if (rw == 0) {   // C row m = q*4+r; all 16 cols identical, take col 0
#pragma unroll
            for (int r = 0; r < 4; r++)
                s_sc[pair][mt * 16 + q * 4 + r] = a4[r];
        }
    }
    __syncthreads();
    float c0 = s_c0[pair][0] + s_c0[pair][1];
    float p = expf((s_sc[pair][lane] + c0) * 0.03125f);
    float rs = p;
    for (int o = 32; o > 0; o >>= 1) rs += __shfl_xor(rs, o);
    s_p[pair][lane] = p;               // both waves write identical values
    if (h == 0 && lane == 0) ws[RS_O + bt] = rs;
    // W accum: wave h covers s = h*32 .. h*32+31; lane covers cv = lane*4..+3
    float4 wa = {0.f, 0.f, 0.f, 0.f};
#pragma unroll 8
    for (int si = 0; si < 32; si++) {
        int s = h * 32 + si;
        float pv = s_p[pair][s];       // own-wave-written: no sync needed
        s16x4 r4 = *(const s16x4*)(vb + (size_t)s_idx[pair][s] * CV + lane * 4);
        wa.x += pv * bf2f(r4.x); wa.y += pv * bf2f(r4.y);
        wa.z += pv * bf2f(r4.z); wa.w += pv * bf2f(r4.w);
    }
    if (h == 1) {
        s_wa[pair][lane][0] = wa.x; s_wa[pair][lane][1] = wa.y;
        s_wa[pair][lane][2] = wa.z; s_wa[pair][lane][3] = wa.w;
    }
    __syncthreads();
    if (h == 0) {
        wa.x += s_wa[pair][lane][0]; wa.y += s_wa[pair][lane][1];
        wa.z += s_wa[pair][lane][2]; wa.w += s_wa[pair][lane][3];
        s16x4 o;
        o.x = f2bf(wa.x); o.y = f2bf(wa.y); o.z = f2bf(wa.z); o.w = f2bf(wa.w);
        ((s16x4*)((short*)(ws + WB_O) + (size_t)bt * CV))[lane] = o;
    }
}

// ---- g_out: out = x + (Wb @ WvpT^T + rs*bv)/denom; 512 blocks x 4 waves,
// ---- 2048 wave-tiles of 32x16 (halved per-wave chain vs 32x32). ----
__global__ void g_out_mfma(const float* __restrict__ x, float* __restrict__ ws,
                           float* __restrict__ out) {
    int w = blockIdx.x * 4 + (threadIdx.x >> 6);   // 2048 tiles
    int m0 = (w >> 6) * 32, n0 = (w & 63) * 16;    // m: bt(1024), n: d(1024)
    int lane = threadIdx.x & 63;
    // denom for batch b = m0>>8: sum RS[b*256 .. +255]
    int b = m0 >> 8;
    float4 r4 = *(const float4*)(ws + RS_O + b * 256 + lane * 4);
    float dn = r4.x + r4.y + r4.z + r4.w;
    for (int o = 32; o > 0; o >>= 1) dn += __shfl_xor(dn, o);
    float inv = 1.0f / dn;
    int rw = lane & 15, q = lane >> 4;
    const short* A  = (const short*)(ws + WB_O)   + (size_t)m0 * CV;
    const short* Bt = (const short*)(ws + WVPT_O) + (size_t)n0 * CV;
    const short* ap0 = A + rw * CV + q * 8;
    const short* ap1 = ap0 + 16 * CV;
    const short* bp0 = Bt + rw * CV + q * 8;
    f32x4 acc[2] = {};
#pragma unroll 4
    for (int kc = 0; kc < CV; kc += 32) {
        bf16x8 a0 = *(const bf16x8*)(ap0 + kc);
        bf16x8 a1 = *(const bf16x8*)(ap1 + kc);
        bf16x8 b0 = *(const bf16x8*)(bp0 + kc);
        acc[0] = __builtin_amdgcn_mfma_f32_16x16x32_bf16(a0, b0, acc[0], 0, 0, 0);
        acc[1] = __builtin_amdgcn_mfma_f32_16x16x32_bf16(a1, b0, acc[1], 0, 0, 0);
    }
    int col = lane & 15;
#pragma unroll
    for (int i = 0; i < 2; i++)
#pragma unroll
        for (int r = 0; r < 4; r++) {
            int row = m0 + i * 16 + q * 4 + r;
            float rs = ws[RS_O + row];
            int cc = n0 + col;
            out[(size_t)row * DIM + cc] =
                x[(size_t)row * DIM + cc] +
                (acc[i][r] + rs * ws[BV_O + cc]) * inv;
        }
}

extern "C" void kernel_launch(void* const* d_in, const int* in_sizes, int n_in,
                              void* d_out, int out_size, void* d_ws, size_t ws_size,
                              hipStream_t stream) {
    (void)in_sizes; (void)n_in; (void)out_size; (void)ws_size;
    const float* x      = (const float*)d_in[0];
    const float* vision = (const float*)d_in[1];
    const void*  mask   = d_in[2];
    const float* Wu     = (const float*)d_in[3];
    const float* bu     = (const float*)d_in[4];
    const float* Wk     = (const float*)d_in[5];
    const float* Wv     = (const float*)d_in[6];
    float* out = (float*)d_out;
    float* ws  = (float*)d_ws;
    int*   wsi = (int*)d_ws;

    stage1<<<2880, 256, 0, stream>>>(vision, Wu, x, Wk, Wv, bu, mask, ws, wsi);
    g_prep_mfma<<<514, 256, 0, stream>>>(ws);
    g_z_mfma<<<256, 256, 0, stream>>>(ws);
    g_attn<<<512, 256, 0, stream>>>(x, ws, wsi);
    g_out_mfma<<<512, 256, 0, stream>>>(x, ws, out);
}